// Round 15
// baseline (587.396 us; speedup 1.0000x reference)
//
#include <hip/hip_runtime.h>

// GTrXL v12: round-14 base + overhead elimination:
//  - inputs->bf16 cvt fused into LN1 epilogue (rows>=4096 already load inputs)
//  - kc/rpT preps dropped: attn issues global_load_lds straight from kvb/rposb
//    (per-lane addresses; only vT still needs a real transpose prep)

typedef __bf16 bf16_t;
typedef __bf16 bf16x4 __attribute__((ext_vector_type(4)));
typedef __bf16 bf16x8 __attribute__((ext_vector_type(8)));
typedef float f32x4 __attribute__((ext_vector_type(4)));

typedef __attribute__((address_space(1))) const void* GPtr;
typedef __attribute__((address_space(3))) void* LPtr;

// ---------------- fp32 -> bf16 convert with output row stride (pos_emb only) -----------
__global__ __launch_bounds__(256) void cvt_kernel(const float* __restrict__ in,
                                                  bf16_t* __restrict__ out, int n4, int ld4) {
  int i = blockIdx.x * 256 + threadIdx.x;
  if (i >= n4) return;
  int row = i >> 8, c = i & 255;
  f32x4 v = ((const f32x4*)in)[i];
  bf16x4 o;
  o[0] = (bf16_t)v[0]; o[1] = (bf16_t)v[1]; o[2] = (bf16_t)v[2]; o[3] = (bf16_t)v[3];
  *(bf16x4*)&out[(size_t)row * ld4 + c * 4] = o;
}

// ---------------- batched weight transpose: W[K][N] f32 -> WT[N][ld] bf16 ----------------
#define NWT 20
struct WtArgs {
  const float* src[NWT];
  bf16_t* dst[NWT];
  int kdim[NWT];
  int ndim[NWT];
  int ld[NWT];
  int tile_end[NWT];
};

__global__ __launch_bounds__(256) void wt_batch(WtArgs a) {
  int t = blockIdx.x;
  int i = 0;
  while (i < NWT - 1 && t >= a.tile_end[i]) ++i;
  int lt = t - (i ? a.tile_end[i - 1] : 0);
  const float* W = a.src[i];
  bf16_t* WT = a.dst[i];
  int K = a.kdim[i], N = a.ndim[i], ld = a.ld[i];
  int ntx = N >> 6;
  int n0 = (lt % ntx) * 64, k0 = (lt / ntx) * 64;
  int tid = threadIdx.x;
  int c = tid & 63, r0 = tid >> 6;
  if (W == nullptr) {  // zero-fill block
    #pragma unroll
    for (int p = 0; p < 16; ++p) {
      int r = r0 + p * 4;
      WT[(size_t)(n0 + r) * ld + k0 + c] = (bf16_t)0.f;
    }
    return;
  }
  __shared__ float tbuf[64][65];
  #pragma unroll
  for (int p = 0; p < 16; ++p) {
    int r = r0 + p * 4;
    tbuf[r][c] = W[(size_t)(k0 + r) * N + n0 + c];
  }
  __syncthreads();
  #pragma unroll
  for (int p = 0; p < 16; ++p) {
    int r = r0 + p * 4;
    WT[(size_t)(n0 + r) * ld + k0 + c] = (bf16_t)tbuf[c][r];
  }
}

// ---------------- LayerNorm over D=1024 (+optional raw-x bf16 side-store) ----------------
__global__ __launch_bounds__(256) void ln_kernel(const float* __restrict__ srcA,
                                                 const float* __restrict__ srcB, int splitRow,
                                                 const float* __restrict__ g,
                                                 const float* __restrict__ be,
                                                 bf16_t* __restrict__ out,
                                                 bf16_t* __restrict__ xcvt, int ldx) {
  const int row = blockIdx.x, tid = threadIdx.x;
  const bool useB = (srcB != nullptr && row >= splitRow);
  const float* src = useB ? srcB + (size_t)(row - splitRow) * 1024
                          : srcA + (size_t)row * 1024;
  f32x4 x = ((const f32x4*)src)[tid];
  if (useB && xcvt != nullptr) {  // fused inputs->bf16 cvt (free: x already loaded)
    bf16x4 xc;
    #pragma unroll
    for (int j = 0; j < 4; ++j) xc[j] = (bf16_t)x[j];
    *(bf16x4*)&xcvt[(size_t)(row - splitRow) * ldx + tid * 4] = xc;
  }
  __shared__ float red[8];
  float s = x[0] + x[1] + x[2] + x[3];
  #pragma unroll
  for (int o = 32; o; o >>= 1) s += __shfl_down(s, o);
  if ((tid & 63) == 0) red[tid >> 6] = s;
  __syncthreads();
  if (tid == 0) red[4] = (red[0] + red[1] + red[2] + red[3]) * (1.f / 1024.f);
  __syncthreads();
  const float mean = red[4];
  f32x4 d = x - mean;
  float s2 = d[0] * d[0] + d[1] * d[1] + d[2] * d[2] + d[3] * d[3];
  #pragma unroll
  for (int o = 32; o; o >>= 1) s2 += __shfl_down(s2, o);
  if ((tid & 63) == 0) red[tid >> 6] = s2;
  __syncthreads();
  if (tid == 0) red[5] = rsqrtf((red[0] + red[1] + red[2] + red[3]) * (1.f / 1024.f) + 1e-5f);
  __syncthreads();
  const float rstd = red[5];
  f32x4 gg = ((const f32x4*)g)[tid], bb = ((const f32x4*)be)[tid];
  bf16x4 o4;
  #pragma unroll
  for (int j = 0; j < 4; ++j) o4[j] = (bf16_t)(d[j] * rstd * gg[j] + bb[j]);
  ((bf16x4*)(out + (size_t)row * 1024))[tid] = o4;
}

// ---------------- epilogue: act 0/1 (bias/relu), act 5 (gate combine) -------------
__device__ __forceinline__ void epi_store(float vv, int row, int colb, int act,
                                          const float* bias, float* Cf, int ldcf, bf16_t* Cb,
                                          int ldcb, const bf16_t* zio, const bf16_t* hp,
                                          const float* xin) {
  if (act <= 1) {
    if (bias) vv += bias[colb];
    if (act == 1) vv = fmaxf(vv, 0.f);
    if (Cf) Cf[(size_t)row * ldcf + colb] = vv;
    if (Cb) Cb[(size_t)row * ldcb + colb] = (bf16_t)vv;
  } else {  // act 5: h=tanh(v+hp); o = x + z*(h-x)
    size_t e = (size_t)row * 1024 + colb;
    float hh = tanhf(vv + (float)hp[e]);
    float xx = xin[e], zz = (float)zio[e];
    float o = xx + zz * (hh - xx);
    if (Cf) Cf[(size_t)row * ldcf + colb] = o;
    if (Cb) Cb[(size_t)row * ldcb + colb] = (bf16_t)o;
  }
}

// ---------------- 128x64-tile MFMA GEMM, BK=64, XOR-swizzled LDS ----------------
__global__ __launch_bounds__(256) void gemm_n64(const bf16_t* __restrict__ A,
                                                const bf16_t* __restrict__ BT,
                                                const float* __restrict__ bias,
                                                float* __restrict__ Cf, int ldcf,
                                                bf16_t* __restrict__ Cb, int ldcb,
                                                const bf16_t* __restrict__ zio,
                                                const bf16_t* __restrict__ hp,
                                                const float* __restrict__ xin,
                                                int M, int N, int K, int act) {
  __shared__ bf16_t As[128 * 64];
  __shared__ bf16_t Bs[64 * 64];
  const int tid = threadIdx.x, lane = tid & 63, wid = tid >> 6;
  const int nx = gridDim.x;
  int flat = blockIdx.y * nx + blockIdx.x;
  int nwg = nx * gridDim.y;
  int q8 = nwg >> 3, r8 = nwg & 7;
  int xcd = flat & 7, idx = flat >> 3;
  int wg = (xcd < r8) ? xcd * (q8 + 1) + idx : r8 * (q8 + 1) + (xcd - r8) * q8 + idx;
  const int m0 = (wg / nx) * 128, n0 = (wg % nx) * 64;
  const int wm = wid * 32;
  const int mrow = lane & 15, kq = lane >> 4;
  f32x4 acc[2][4] = {};
  const int lrow = wid * 8 + (lane >> 3);
  const int swsrc = (((lane & 7) ^ ((lane >> 3) & 7)) << 3);
  for (int k0 = 0; k0 < K; k0 += 64) {
    #pragma unroll
    for (int i = 0; i < 4; ++i) {
      const bf16_t* ga = A + (size_t)(m0 + i * 32 + lrow) * K + k0 + swsrc;
      __builtin_amdgcn_global_load_lds((GPtr)ga, (LPtr)(&As[i * 2048 + wid * 512]), 16, 0, 0);
    }
    #pragma unroll
    for (int i = 0; i < 2; ++i) {
      const bf16_t* gb = BT + (size_t)(n0 + i * 32 + lrow) * K + k0 + swsrc;
      __builtin_amdgcn_global_load_lds((GPtr)gb, (LPtr)(&Bs[i * 2048 + wid * 512]), 16, 0, 0);
    }
    __syncthreads();
    bf16x8 af[2][2], bfr[4][2];
    #pragma unroll
    for (int i = 0; i < 2; ++i) {
      int row = wm + i * 16 + mrow;
      #pragma unroll
      for (int ks = 0; ks < 2; ++ks)
        af[i][ks] = *(const bf16x8*)&As[row * 64 + ((ks * 32 + kq * 8) ^ ((row & 7) << 3))];
    }
    #pragma unroll
    for (int j = 0; j < 4; ++j) {
      int row = j * 16 + mrow;
      #pragma unroll
      for (int ks = 0; ks < 2; ++ks)
        bfr[j][ks] = *(const bf16x8*)&Bs[row * 64 + ((ks * 32 + kq * 8) ^ ((row & 7) << 3))];
    }
    #pragma unroll
    for (int i = 0; i < 2; ++i)
      #pragma unroll
      for (int j = 0; j < 4; ++j)
        #pragma unroll
        for (int ks = 0; ks < 2; ++ks)
          acc[i][j] = __builtin_amdgcn_mfma_f32_16x16x32_bf16(af[i][ks], bfr[j][ks], acc[i][j],
                                                              0, 0, 0);
    __syncthreads();
  }
  #pragma unroll
  for (int i = 0; i < 2; ++i)
    #pragma unroll
    for (int j = 0; j < 4; ++j) {
      int colb = n0 + j * 16 + mrow;
      #pragma unroll
      for (int r2 = 0; r2 < 4; ++r2) {
        int row = m0 + wm + i * 16 + kq * 4 + r2;
        epi_store(acc[i][j][r2], row, colb, act, bias, Cf, ldcf, Cb, ldcb, zio, hp, xin);
      }
    }
}

// ---------------- 8-phase 256^2 GEMM ----------------
template <int MH, int NH>
__device__ __forceinline__ void mfma_quad(f32x4 (&acc)[8][4], bf16x8 (&a)[4][2],
                                          bf16x8 (&bfr)[4][2]) {
  #pragma unroll
  for (int ii = 0; ii < 4; ++ii)
    #pragma unroll
    for (int jj = 0; jj < 2; ++jj)
      #pragma unroll
      for (int ks = 0; ks < 2; ++ks)
        acc[MH * 4 + ii][NH * 2 + jj] = __builtin_amdgcn_mfma_f32_16x16x32_bf16(
            a[ii][ks], bfr[NH * 2 + jj][ks], acc[MH * 4 + ii][NH * 2 + jj], 0, 0, 0);
}

#define PH_SYNC()                                                                             \
  __builtin_amdgcn_s_barrier();                                                               \
  asm volatile("s_waitcnt lgkmcnt(0)" ::: "memory");                                          \
  __builtin_amdgcn_sched_barrier(0);                                                          \
  __builtin_amdgcn_s_setprio(1)

#define PH_END()                                                                              \
  __builtin_amdgcn_s_setprio(0);                                                              \
  __builtin_amdgcn_s_barrier();                                                               \
  __builtin_amdgcn_sched_barrier(0)

#define PH_END_VM()                                                                           \
  __builtin_amdgcn_s_setprio(0);                                                              \
  asm volatile("s_waitcnt vmcnt(4)" ::: "memory");                                            \
  __builtin_amdgcn_s_barrier();                                                               \
  __builtin_amdgcn_sched_barrier(0)

// ACT: 0 bias, 1 bias+relu, 4 gate pass1 (N=3072: rx | z | hpart, block-uniform regions)
template <int ACT>
__global__ __launch_bounds__(512, 2) void gemm256(const bf16_t* __restrict__ A,
                                                  const bf16_t* __restrict__ BT,
                                                  const float* __restrict__ bias,
                                                  bf16_t* __restrict__ Cb,
                                                  bf16_t* __restrict__ zio,
                                                  bf16_t* __restrict__ hp,
                                                  const float* __restrict__ xin,
                                                  int M, int N, int K) {
  __shared__ bf16_t lds[65536];
  const int tid = threadIdx.x, lane = tid & 63, w = tid >> 6;
  const int mrow = lane & 15, kq = lane >> 4;
  const int nx = N >> 8;
  int nwg = gridDim.x;
  int flat = blockIdx.x;
  int q8 = nwg >> 3, r8 = nwg & 7;
  int xcd = flat & 7, idxb = flat >> 3;
  int wg = (xcd < r8) ? xcd * (q8 + 1) + idxb : r8 * (q8 + 1) + (xcd - r8) * q8 + idxb;
  const int m0 = (wg / nx) * 256, n0 = (wg % nx) * 256;

  const bf16_t* pA = A + (size_t)m0 * K;
  const bf16_t* pB = BT + (size_t)n0 * K;

  auto stage = [&](const bf16_t* base, int kt, int hh, int buf, int area) {
    #pragma unroll
    for (int li = 0; li < 2; ++li) {
      int row = li * 64 + w * 8 + (lane >> 3);
      const bf16_t* src =
          base + (size_t)(hh * 128 + row) * K + kt * 64 + (((lane & 7) ^ (lane >> 3)) << 3);
      __builtin_amdgcn_global_load_lds(
          (GPtr)src, (LPtr)&lds[buf * 32768 + area * 16384 + hh * 8192 + li * 4096 + w * 512],
          16, 0, 0);
    }
  };
  auto ldA = [&](int buf, int i, int ks) -> bf16x8 {
    int row = i * 16 + mrow;
    int off = (row << 6) + ((ks * 32 + kq * 8) ^ ((row & 7) << 3));
    return *(const bf16x8*)&lds[buf * 32768 + (w >> 2) * 8192 + off];
  };
  auto ldB = [&](int buf, int j, int ks) -> bf16x8 {
    int row = (w & 1) * 64 + j * 16 + mrow;
    int off = (row << 6) + ((ks * 32 + kq * 8) ^ ((row & 7) << 3));
    return *(const bf16x8*)&lds[buf * 32768 + 16384 + ((w & 3) >> 1) * 8192 + off];
  };

  f32x4 acc[8][4] = {};
  bf16x8 a[4][2], bfr[4][2];

  const int KT = K >> 6;
  stage(pA, 0, 0, 0, 0);
  stage(pA, 0, 1, 0, 0);
  stage(pB, 0, 0, 0, 1);
  stage(pB, 0, 1, 0, 1);
  stage(pB, 1, 0, 1, 1);
  stage(pB, 1, 1, 1, 1);
  asm volatile("s_waitcnt vmcnt(4)" ::: "memory");
  __builtin_amdgcn_s_barrier();
  __builtin_amdgcn_sched_barrier(0);

  for (int it = 0; it < KT / 2; ++it) {
    int kt = 2 * it;
    int ktA1 = min(kt + 1, KT - 1);
    int kt2 = min(kt + 2, KT - 1);
    int kt3 = min(kt + 3, KT - 1);
    #pragma unroll
    for (int ii = 0; ii < 4; ++ii) { a[ii][0] = ldA(0, ii, 0); a[ii][1] = ldA(0, ii, 1); }
    #pragma unroll
    for (int jj = 0; jj < 2; ++jj) { bfr[jj][0] = ldB(0, jj, 0); bfr[jj][1] = ldB(0, jj, 1); }
    stage(pA, ktA1, 0, 1, 0);
    PH_SYNC(); mfma_quad<0, 0>(acc, a, bfr); PH_END();
    #pragma unroll
    for (int jj = 0; jj < 2; ++jj) { bfr[2 + jj][0] = ldB(0, 2 + jj, 0); bfr[2 + jj][1] = ldB(0, 2 + jj, 1); }
    stage(pA, ktA1, 1, 1, 0);
    PH_SYNC(); mfma_quad<0, 1>(acc, a, bfr); PH_END();
    #pragma unroll
    for (int ii = 0; ii < 4; ++ii) { a[ii][0] = ldA(0, 4 + ii, 0); a[ii][1] = ldA(0, 4 + ii, 1); }
    stage(pB, kt2, 0, 0, 1);
    PH_SYNC(); mfma_quad<1, 0>(acc, a, bfr); PH_END();
    stage(pB, kt2, 1, 0, 1);
    PH_SYNC(); mfma_quad<1, 1>(acc, a, bfr); PH_END_VM();
    #pragma unroll
    for (int ii = 0; ii < 4; ++ii) { a[ii][0] = ldA(1, ii, 0); a[ii][1] = ldA(1, ii, 1); }
    #pragma unroll
    for (int jj = 0; jj < 2; ++jj) { bfr[jj][0] = ldB(1, jj, 0); bfr[jj][1] = ldB(1, jj, 1); }
    stage(pA, kt2, 0, 0, 0);
    PH_SYNC(); mfma_quad<0, 0>(acc, a, bfr); PH_END();
    #pragma unroll
    for (int jj = 0; jj < 2; ++jj) { bfr[2 + jj][0] = ldB(1, 2 + jj, 0); bfr[2 + jj][1] = ldB(1, 2 + jj, 1); }
    stage(pA, kt2, 1, 0, 0);
    PH_SYNC(); mfma_quad<0, 1>(acc, a, bfr); PH_END();
    #pragma unroll
    for (int ii = 0; ii < 4; ++ii) { a[ii][0] = ldA(1, 4 + ii, 0); a[ii][1] = ldA(1, 4 + ii, 1); }
    stage(pB, kt3, 0, 1, 1);
    PH_SYNC(); mfma_quad<1, 0>(acc, a, bfr); PH_END();
    stage(pB, kt3, 1, 1, 1);
    PH_SYNC(); mfma_quad<1, 1>(acc, a, bfr); PH_END_VM();
  }

  if (ACT <= 1) {
    #pragma unroll
    for (int i = 0; i < 8; ++i)
      #pragma unroll
      for (int j = 0; j < 4; ++j) {
        int colb = n0 + (w & 3) * 64 + j * 16 + mrow;
        float bv = bias ? bias[colb] : 0.f;
        #pragma unroll
        for (int r2 = 0; r2 < 4; ++r2) {
          int row = m0 + (w >> 2) * 128 + i * 16 + kq * 4 + r2;
          float vv = acc[i][j][r2] + bv;
          if (ACT == 1) vv = fmaxf(vv, 0.f);
          Cb[(size_t)row * N + colb] = (bf16_t)vv;
        }
      }
  } else {  // ACT == 4: block-uniform regions (1024-wide)
    if (n0 < 1024) {
      #pragma unroll
      for (int i = 0; i < 8; ++i)
        #pragma unroll
        for (int j = 0; j < 4; ++j) {
          int colb = n0 + (w & 3) * 64 + j * 16 + mrow;
          #pragma unroll
          for (int r2 = 0; r2 < 4; ++r2) {
            int row = m0 + (w >> 2) * 128 + i * 16 + kq * 4 + r2;
            float r = 1.f / (1.f + __expf(-acc[i][j][r2]));
            Cb[(size_t)row * 1024 + colb] = (bf16_t)(r * xin[(size_t)row * 1024 + colb]);
          }
        }
    } else if (n0 < 2048) {
      #pragma unroll
      for (int i = 0; i < 8; ++i)
        #pragma unroll
        for (int j = 0; j < 4; ++j) {
          int colz = n0 - 1024 + (w & 3) * 64 + j * 16 + mrow;
          float bv = bias[colz];
          #pragma unroll
          for (int r2 = 0; r2 < 4; ++r2) {
            int row = m0 + (w >> 2) * 128 + i * 16 + kq * 4 + r2;
            float z = 1.f / (1.f + __expf(-(acc[i][j][r2] - bv)));
            zio[(size_t)row * 1024 + colz] = (bf16_t)z;
          }
        }
    } else {
      #pragma unroll
      for (int i = 0; i < 8; ++i)
        #pragma unroll
        for (int j = 0; j < 4; ++j) {
          int colh = n0 - 2048 + (w & 3) * 64 + j * 16 + mrow;
          #pragma unroll
          for (int r2 = 0; r2 < 4; ++r2) {
            int row = m0 + (w >> 2) * 128 + i * 16 + kq * 4 + r2;
            hp[(size_t)row * 1024 + colh] = (bf16_t)acc[i][j][r2];
          }
        }
    }
  }
}

// ---------------- vT prep only (kv stride 2048) ----------------
__global__ __launch_bounds__(256) void prep_kernel(const bf16_t* __restrict__ kv,
                                                   bf16_t* __restrict__ vT) {
  int bh = blockIdx.y, ft = blockIdx.x;
  int b = bh >> 4, h = bh & 15;
  int tid = threadIdx.x;
  __shared__ bf16_t t[64][68];
  {
    int dq = (tid & 15) * 4, fr = tid >> 4;
    #pragma unroll
    for (int p = 0; p < 4; ++p) {
      int fi = fr + p * 16;
      const bf16_t* src = kv + ((size_t)((ft * 64 + fi) * 8 + b)) * 2048 + 1024 + h * 64 + dq;
      *(bf16x4*)&t[fi][dq] = *(const bf16x4*)src;
    }
  }
  __syncthreads();
  {
    int fl = tid & 63, dr = tid >> 6;
    #pragma unroll
    for (int p = 0; p < 16; ++p) {
      int d = dr + p * 4;
      vT[((size_t)(bh * 64 + d)) * 1024 + ft * 64 + fl] = t[fl][d];
    }
  }
}

// ---------------- attention v6d: direct K/rpos reads (strided), vT staged ----------------
__global__ __launch_bounds__(256) void attn_kernel(const bf16_t* __restrict__ q,
                                                   const bf16_t* __restrict__ kv,
                                                   const bf16_t* __restrict__ rposb,
                                                   const bf16_t* __restrict__ vT,
                                                   const float* __restrict__ u,
                                                   const float* __restrict__ v,
                                                   bf16_t* __restrict__ av) {
  const int bh = blockIdx.x, st = blockIdx.y;
  const int b = bh >> 4, h = bh & 15;
  const int s0 = st * 16;
  const int tid = threadIdx.x, lane = tid & 63, w = tid >> 6;
  const int mrow = lane & 15, kq = lane >> 4;

  __shared__ bf16_t sc[16 * 1032];
  __shared__ bf16_t slots[4 * 2 * 1024];
  __shared__ float rrecip[16];

  bf16x8 afu[2], afv[2];
  {
    const bf16_t* qp = q + ((size_t)((s0 + mrow) * 8 + b)) * 1024 + h * 64 + kq * 8;
    bf16x8 q0 = *(const bf16x8*)qp;
    bf16x8 q1 = *(const bf16x8*)(qp + 32);
    const float* ub = u + h * 64 + kq * 8;
    const float* vb = v + h * 64 + kq * 8;
    #pragma unroll
    for (int j = 0; j < 8; ++j) {
      float f0 = (float)q0[j], f1 = (float)q1[j];
      afu[0][j] = (bf16_t)((f0 + ub[j]) * 0.125f);
      afu[1][j] = (bf16_t)((f1 + ub[32 + j]) * 0.125f);
      afv[0][j] = (bf16_t)((f0 + vb[j]) * 0.125f);
      afv[1][j] = (bf16_t)((f1 + vb[32 + j]) * 0.125f);
    }
  }

  const int nf1 = (s0 + 543) >> 4;
  const int jt0 = (s0 >= 496) ? 0 : ((496 - s0) >> 4);
  // K rows: kv[(f*8+b)*2048 + h*64 + ...] -> base kv + b*2048 + h*64, f-stride 16384
  const bf16_t* kcb = kv + (size_t)b * 2048 + h * 64;
  // rpos rows: rposb[j*1024 + h*64 + ...] -> base rposb + h*64, j-stride 1024
  const bf16_t* rpb = rposb + h * 64;
  const int swzel = ((lane & 7) ^ (lane >> 3)) * 8;
  const int rdsw = (mrow & 7) << 4;

  auto issueT = [&](const bf16_t* base, size_t rstride, int idx, int tile) {
    int slot = idx & 1;
    #pragma unroll
    for (int li = 0; li < 2; ++li) {
      const bf16_t* src = base + (size_t)(tile * 16 + li * 8 + (lane >> 3)) * rstride + swzel;
      __builtin_amdgcn_global_load_lds((GPtr)src,
                                       (LPtr)&slots[w * 2048 + slot * 1024 + li * 512], 16, 0, 0);
    }
  };
  auto slotB = [&](int idx, bf16x8& b0, bf16x8& b1) {
    const bf16_t* sb = &slots[w * 2048 + (idx & 1) * 1024];
    b0 = *(const bf16x8*)&sb[(mrow * 128 + ((kq * 16) ^ rdsw)) >> 1];
    b1 = *(const bf16x8*)&sb[(mrow * 128 + ((64 + kq * 16) ^ rdsw)) >> 1];
  };

  // phase 1: content scores (K direct from kv, f-stride 16384)
  {
    int ncw = (nf1 > w) ? (nf1 - w + 3) >> 2 : 0;
    if (ncw > 0) issueT(kcb, 16384, 0, w);
    if (ncw > 1) issueT(kcb, 16384, 1, w + 4);
    for (int i = 0; i < ncw; ++i) {
      if (i + 1 < ncw) asm volatile("s_waitcnt vmcnt(2)" ::: "memory");
      else asm volatile("s_waitcnt vmcnt(0)" ::: "memory");
      __builtin_amdgcn_sched_barrier(0);
      bf16x8 b0, b1;
      slotB(i, b0, b1);
      f32x4 cc = {0.f, 0.f, 0.f, 0.f};
      cc = __builtin_amdgcn_mfma_f32_16x16x32_bf16(afu[0], b0, cc, 0, 0, 0);
      cc = __builtin_amdgcn_mfma_f32_16x16x32_bf16(afu[1], b1, cc, 0, 0, 0);
      int fb = (w + 4 * i) * 16 + mrow;
      #pragma unroll
      for (int r2 = 0; r2 < 4; ++r2) sc[(kq * 4 + r2) * 1032 + fb] = (bf16_t)cc[r2];
      __builtin_amdgcn_sched_barrier(0);
      if (i + 2 < ncw) issueT(kcb, 16384, i + 2, w + 4 * (i + 2));
    }
  }
  __syncthreads();

  // phase 2: position scores (rpos direct, j-stride 1024), RMW scatter f = j-511+s
  {
    int navail = 64 - jt0;
    int npw = (navail > w) ? (navail - w + 3) >> 2 : 0;
    if (npw > 0) issueT(rpb, 1024, 0, jt0 + w);
    if (npw > 1) issueT(rpb, 1024, 1, jt0 + w + 4);
    for (int i = 0; i < npw; ++i) {
      if (i + 1 < npw) asm volatile("s_waitcnt vmcnt(2)" ::: "memory");
      else asm volatile("s_waitcnt vmcnt(0)" ::: "memory");
      __builtin_amdgcn_sched_barrier(0);
      bf16x8 b0, b1;
      slotB(i, b0, b1);
      f32x4 cc = {0.f, 0.f, 0.f, 0.f};
      cc = __builtin_amdgcn_mfma_f32_16x16x32_bf16(afv[0], b0, cc, 0, 0, 0);
      cc = __builtin_amdgcn_mfma_f32_16x16x32_bf16(afv[1], b1, cc, 0, 0, 0);
      int jb = (jt0 + w + 4 * i) * 16 + mrow - 511 + s0;
      #pragma unroll
      for (int r2 = 0; r2 < 4; ++r2) {
        int srow = kq * 4 + r2;
        int f = jb + srow;
        if (f >= 0) {
          float old = (float)sc[srow * 1032 + f];
          sc[srow * 1032 + f] = (bf16_t)(old + cc[r2]);
        }
      }
      __builtin_amdgcn_sched_barrier(0);
      if (i + 2 < npw) issueT(rpb, 1024, i + 2, jt0 + w + 4 * (i + 2));
    }
  }
  __syncthreads();

  // phase 3: masked softmax
  #pragma unroll
  for (int rr = 0; rr < 4; ++rr) {
    int row = w * 4 + rr;
    int fmx = s0 + row;
    bf16x8 c0 = *(const bf16x8*)&sc[row * 1032 + lane * 8];
    bf16x8 c1 = *(const bf16x8*)&sc[row * 1032 + 512 + lane * 8];
    float lo[8], hi[8];
    float mx = -1e30f;
    #pragma unroll
    for (int i = 0; i < 8; ++i) {
      lo[i] = (float)c0[i];
      mx = fmaxf(mx, lo[i]);
    }
    #pragma unroll
    for (int i = 0; i < 8; ++i) {
      hi[i] = (float)c1[i];
      if (lane * 8 + i <= fmx) mx = fmaxf(mx, hi[i]);
    }
    #pragma unroll
    for (int o = 32; o; o >>= 1) mx = fmaxf(mx, __shfl_xor(mx, o));
    float sum = 0.f;
    bf16x8 e0, e1;
    #pragma unroll
    for (int i = 0; i < 8; ++i) {
      float e = __expf(lo[i] - mx);
      sum += e;
      e0[i] = (bf16_t)e;
    }
    #pragma unroll
    for (int i = 0; i < 8; ++i) {
      float e = (lane * 8 + i <= fmx) ? __expf(hi[i] - mx) : 0.f;
      sum += e;
      e1[i] = (bf16_t)e;
    }
    *(bf16x8*)&sc[row * 1032 + lane * 8] = e0;
    *(bf16x8*)&sc[row * 1032 + 512 + lane * 8] = e1;
    #pragma unroll
    for (int o = 32; o; o >>= 1) sum += __shfl_xor(sum, o);
    if (lane == 0) rrecip[row] = 1.f / sum;
  }
  __syncthreads();

  // phase 4: AV
  {
    int nkk = (s0 + 559) >> 5;
    const bf16_t* vtb = vT + (size_t)(bh * 64 + w * 16) * 1024;
    auto issueV = [&](int idx, int kk) {
      int slot = idx & 1;
      const bf16_t* src = vtb + (size_t)(lane >> 2) * 1024 + kk * 32 +
                          (((lane & 3) ^ ((lane >> 2) & 3)) << 3);
      __builtin_amdgcn_global_load_lds((GPtr)src, (LPtr)&slots[w * 2048 + slot * 1024], 16, 0, 0);
    };
    f32x4 acc = {0.f, 0.f, 0.f, 0.f};
    issueV(0, 0);
    if (nkk > 1) issueV(1, 1);
    for (int kk = 0; kk < nkk; ++kk) {
      if (kk + 1 < nkk) asm volatile("s_waitcnt vmcnt(1)" ::: "memory");
      else asm volatile("s_waitcnt vmcnt(0)" ::: "memory");
      __builtin_amdgcn_sched_barrier(0);
      const bf16_t* sb = &slots[w * 2048 + (kk & 1) * 1024];
      bf16x8 bv = *(const bf16x8*)&sb[mrow * 32 + ((kq ^ (mrow & 3)) << 3)];
      bf16x8 af = *(const bf16x8*)&sc[mrow * 1032 + kk * 32 + kq * 8];
      acc = __builtin_amdgcn_mfma_f32_16x16x32_bf16(af, bv, acc, 0, 0, 0);
      __builtin_amdgcn_sched_barrier(0);
      if (kk + 2 < nkk) issueV(kk + 2, kk + 2);
    }
    #pragma unroll
    for (int r2 = 0; r2 < 4; ++r2) {
      int srow = kq * 4 + r2;
      float ov = acc[r2] * rrecip[srow];
      av[((size_t)((s0 + srow) * 8 + b)) * 1024 + h * 64 + w * 16 + mrow] = (bf16_t)ov;
    }
  }
}

// ---------------- host ----------------
extern "C" void kernel_launch(void* const* d_in, const int* in_sizes, int n_in,
                              void* d_out, int out_size, void* d_ws, size_t ws_size,
                              hipStream_t stream) {
  const float* inputs = (const float*)d_in[0];
  const float* pos_emb = (const float*)d_in[1];
  const float* memory = (const float*)d_in[2];
  const float* u = (const float*)d_in[3];
  const float* v = (const float*)d_in[4];
  const float* Wkv = (const float*)d_in[6];
  const float* bkv = (const float*)d_in[7];
  const float* Wq = (const float*)d_in[8];
  const float* bq = (const float*)d_in[9];
  const float* Wpos = (const float*)d_in[10];
  const float* bpos = (const float*)d_in[11];
  const float* Wproj = (const float*)d_in[12];
  const float* bproj = (const float*)d_in[13];
  const float* ln1_g = (const float*)d_in[14];
  const float* ln1_b = (const float*)d_in[15];
  const float* ln2_g = (const float*)d_in[16];
  const float* ln2_b = (const float*)d_in[17];
  const float* g1_bg = (const float*)d_in[24];
  const float* g2_bg = (const float*)d_in[31];
  const float* mlp_W1 = (const float*)d_in[32];
  const float* mlp_b1 = (const float*)d_in[33];
  const float* mlp_W2 = (const float*)d_in[34];
  const float* mlp_b2 = (const float*)d_in[35];

  char* ws = (char*)d_ws;
  const size_t MB = 1ull << 20;
  bf16_t* x1 = (bf16_t*)(ws + 0);
  bf16_t* kvb = (bf16_t*)(ws + 16 * MB);    // 32MB, read by attn (K) + prep (V)
  bf16_t* qb = (bf16_t*)(ws + 48 * MB);
  bf16_t* peb = (bf16_t*)(ws + 56 * MB);
  bf16_t* rposb = (bf16_t*)(ws + 58 * MB);  // read by attn directly
  bf16_t* vTb = (bf16_t*)(ws + 76 * MB);
  bf16_t* avb = (bf16_t*)(ws + 94 * MB);
  bf16_t* yx1 = (bf16_t*)(ws + 102 * MB);
  bf16_t* rxb = (bf16_t*)(ws + 0);
  bf16_t* zb = (bf16_t*)(ws + 8 * MB);
  bf16_t* hpb = (bf16_t*)(ws + 16 * MB);
  float* o1f = (float*)(ws + 24 * MB);
  bf16_t* x2b = (bf16_t*)(ws + 40 * MB);
  bf16_t* m1b = (bf16_t*)(ws + 48 * MB);
  bf16_t* yx2 = (bf16_t*)(ws + 80 * MB);
  bf16_t* WkvT = (bf16_t*)(ws + 134 * MB);
  bf16_t* WqT = (bf16_t*)(ws + 138 * MB);
  bf16_t* WposT = (bf16_t*)(ws + 140 * MB);
  bf16_t* WprojT = (bf16_t*)(ws + 142 * MB);
  bf16_t* W1T = (bf16_t*)(ws + 144 * MB);
  bf16_t* W2T = (bf16_t*)(ws + 152 * MB);
  bf16_t* g1p = (bf16_t*)(ws + 160 * MB);
  bf16_t* g1ug = (bf16_t*)(ws + 172 * MB);
  bf16_t* g2p = (bf16_t*)(ws + 174 * MB);
  bf16_t* g2ug = (bf16_t*)(ws + 186 * MB);

  WtArgs wa;
  {
    const float* srcs[NWT] = {Wkv, Wq, Wpos, Wproj, mlp_W1, mlp_W2,
                              (const float*)d_in[18], (const float*)d_in[19],
                              (const float*)d_in[20], (const float*)d_in[21],
                              (const float*)d_in[22], nullptr, (const float*)d_in[23],
                              (const float*)d_in[25], (const float*)d_in[26],
                              (const float*)d_in[27], (const float*)d_in[28],
                              (const float*)d_in[29], nullptr, (const float*)d_in[30]};
    bf16_t* dsts[NWT] = {WkvT, WqT, WposT, WprojT, W1T, W2T,
                         g1p, g1p + 1024, g1p + (size_t)1024 * 2048,
                         g1p + (size_t)1024 * 2048 + 1024, g1p + (size_t)2048 * 2048,
                         g1p + (size_t)2048 * 2048 + 1024, g1ug,
                         g2p, g2p + 1024, g2p + (size_t)1024 * 2048,
                         g2p + (size_t)1024 * 2048 + 1024, g2p + (size_t)2048 * 2048,
                         g2p + (size_t)2048 * 2048 + 1024, g2ug};
    int kds[NWT] = {1024, 1024, 1024, 1024, 1024, 4096, 1024, 1024, 1024, 1024,
                    1024, 1024, 1024, 1024, 1024, 1024, 1024, 1024, 1024, 1024};
    int nds[NWT] = {2048, 1024, 1024, 1024, 4096, 1024, 1024, 1024, 1024, 1024,
                    1024, 1024, 1024, 1024, 1024, 1024, 1024, 1024, 1024, 1024};
    int lds_[NWT] = {1024, 1024, 1024, 1024, 1024, 4096, 2048, 2048, 2048, 2048,
                     2048, 2048, 1024, 2048, 2048, 2048, 2048, 2048, 2048, 1024};
    int cum = 0;
    for (int i = 0; i < NWT; ++i) {
      wa.src[i] = srcs[i];
      wa.dst[i] = dsts[i];
      wa.kdim[i] = kds[i];
      wa.ndim[i] = nds[i];
      wa.ld[i] = lds_[i];
      cum += (nds[i] >> 6) * (kds[i] >> 6);
      wa.tile_end[i] = cum;
    }
    wt_batch<<<cum, 256, 0, stream>>>(wa);
  }

  cvt_kernel<<<1024, 256, 0, stream>>>(pos_emb, peb, 262144, 1024);
  // LN1 with fused inputs->bf16 side-store into yx1 x-half
  ln_kernel<<<8192, 256, 0, stream>>>(memory, inputs, 4096, ln1_g, ln1_b, x1, yx1 + 1024, 2048);

  auto g64 = [&](const bf16_t* A, const bf16_t* BT, const float* bias, float* Cf, int ldcf,
                 bf16_t* Cb, int ldcb, const bf16_t* zio, const bf16_t* hp, const float* xin,
                 int M, int N, int K, int act) {
    gemm_n64<<<dim3(N / 64, M / 128), 256, 0, stream>>>(A, BT, bias, Cf, ldcf, Cb, ldcb, zio, hp,
                                                        xin, M, N, K, act);
  };

  gemm256<0><<<(8192 / 256) * (2048 / 256), 512, 0, stream>>>(x1, WkvT, bkv, kvb, nullptr,
                                                              nullptr, nullptr, 8192, 2048, 1024);
  g64(x1 + (size_t)4096 * 1024, WqT, bq, nullptr, 0, qb, 1024, nullptr, nullptr, nullptr, 4096,
      1024, 1024, 0);
  g64(peb, WposT, bpos, nullptr, 0, rposb, 1024, nullptr, nullptr, nullptr, 1024, 1024, 1024, 0);
  prep_kernel<<<dim3(16, 128), 256, 0, stream>>>(kvb, vTb);
  attn_kernel<<<dim3(128, 32), 256, 0, stream>>>(qb, kvb, rposb, vTb, u, v, avb);
  g64(avb, WprojT, bproj, nullptr, 0, yx1, 2048, nullptr, nullptr, nullptr, 4096, 1024, 1024, 1);

  // GRU gate 1
  gemm256<4><<<(4096 / 256) * (3072 / 256), 512, 0, stream>>>(yx1, g1p, g1_bg, rxb, zb, hpb,
                                                              inputs, 4096, 3072, 2048);
  g64(rxb, g1ug, nullptr, o1f, 1024, yx2 + 1024, 2048, zb, hpb, inputs, 4096, 1024, 1024, 5);

  ln_kernel<<<4096, 256, 0, stream>>>(o1f, nullptr, 1 << 30, ln2_g, ln2_b, x2b, nullptr, 0);
  gemm256<1><<<(4096 / 256) * (4096 / 256), 512, 0, stream>>>(x2b, W1T, mlp_b1, m1b, nullptr,
                                                              nullptr, nullptr, 4096, 4096, 1024);
  g64(m1b, W2T, mlp_b2, nullptr, 0, yx2, 2048, nullptr, nullptr, nullptr, 4096, 1024, 4096, 1);

  // GRU gate 2
  gemm256<4><<<(4096 / 256) * (3072 / 256), 512, 0, stream>>>(yx2, g2p, g2_bg, rxb, zb, hpb, o1f,
                                                              4096, 3072, 2048);
  g64(rxb, g2ug, nullptr, (float*)d_out, 1024, nullptr, 0, zb, hpb, o1f, 4096, 1024, 1024, 5);
}

// Round 16
// 584.548 us; speedup vs baseline: 1.0049x; 1.0049x over previous
//
#include <hip/hip_runtime.h>

// GTrXL v13: best-of composition — round-14 attn (kc/rpT staged, 132us) +
// round-15 LN-fused inputs cvt (one launch fewer). 3-way prep restored.

typedef __bf16 bf16_t;
typedef __bf16 bf16x4 __attribute__((ext_vector_type(4)));
typedef __bf16 bf16x8 __attribute__((ext_vector_type(8)));
typedef float f32x4 __attribute__((ext_vector_type(4)));

typedef __attribute__((address_space(1))) const void* GPtr;
typedef __attribute__((address_space(3))) void* LPtr;

// ---------------- fp32 -> bf16 convert (pos_emb only) ----------------
__global__ __launch_bounds__(256) void cvt_kernel(const float* __restrict__ in,
                                                  bf16_t* __restrict__ out, int n4, int ld4) {
  int i = blockIdx.x * 256 + threadIdx.x;
  if (i >= n4) return;
  int row = i >> 8, c = i & 255;
  f32x4 v = ((const f32x4*)in)[i];
  bf16x4 o;
  o[0] = (bf16_t)v[0]; o[1] = (bf16_t)v[1]; o[2] = (bf16_t)v[2]; o[3] = (bf16_t)v[3];
  *(bf16x4*)&out[(size_t)row * ld4 + c * 4] = o;
}

// ---------------- batched weight transpose: W[K][N] f32 -> WT[N][ld] bf16 ----------------
#define NWT 20
struct WtArgs {
  const float* src[NWT];
  bf16_t* dst[NWT];
  int kdim[NWT];
  int ndim[NWT];
  int ld[NWT];
  int tile_end[NWT];
};

__global__ __launch_bounds__(256) void wt_batch(WtArgs a) {
  int t = blockIdx.x;
  int i = 0;
  while (i < NWT - 1 && t >= a.tile_end[i]) ++i;
  int lt = t - (i ? a.tile_end[i - 1] : 0);
  const float* W = a.src[i];
  bf16_t* WT = a.dst[i];
  int K = a.kdim[i], N = a.ndim[i], ld = a.ld[i];
  int ntx = N >> 6;
  int n0 = (lt % ntx) * 64, k0 = (lt / ntx) * 64;
  int tid = threadIdx.x;
  int c = tid & 63, r0 = tid >> 6;
  if (W == nullptr) {  // zero-fill block
    #pragma unroll
    for (int p = 0; p < 16; ++p) {
      int r = r0 + p * 4;
      WT[(size_t)(n0 + r) * ld + k0 + c] = (bf16_t)0.f;
    }
    return;
  }
  __shared__ float tbuf[64][65];
  #pragma unroll
  for (int p = 0; p < 16; ++p) {
    int r = r0 + p * 4;
    tbuf[r][c] = W[(size_t)(k0 + r) * N + n0 + c];
  }
  __syncthreads();
  #pragma unroll
  for (int p = 0; p < 16; ++p) {
    int r = r0 + p * 4;
    WT[(size_t)(n0 + r) * ld + k0 + c] = (bf16_t)tbuf[c][r];
  }
}

// ---------------- LayerNorm over D=1024 (+optional raw-x bf16 side-store) ----------------
__global__ __launch_bounds__(256) void ln_kernel(const float* __restrict__ srcA,
                                                 const float* __restrict__ srcB, int splitRow,
                                                 const float* __restrict__ g,
                                                 const float* __restrict__ be,
                                                 bf16_t* __restrict__ out,
                                                 bf16_t* __restrict__ xcvt, int ldx) {
  const int row = blockIdx.x, tid = threadIdx.x;
  const bool useB = (srcB != nullptr && row >= splitRow);
  const float* src = useB ? srcB + (size_t)(row - splitRow) * 1024
                          : srcA + (size_t)row * 1024;
  f32x4 x = ((const f32x4*)src)[tid];
  if (useB && xcvt != nullptr) {  // fused inputs->bf16 cvt (free: x already loaded)
    bf16x4 xc;
    #pragma unroll
    for (int j = 0; j < 4; ++j) xc[j] = (bf16_t)x[j];
    *(bf16x4*)&xcvt[(size_t)(row - splitRow) * ldx + tid * 4] = xc;
  }
  __shared__ float red[8];
  float s = x[0] + x[1] + x[2] + x[3];
  #pragma unroll
  for (int o = 32; o; o >>= 1) s += __shfl_down(s, o);
  if ((tid & 63) == 0) red[tid >> 6] = s;
  __syncthreads();
  if (tid == 0) red[4] = (red[0] + red[1] + red[2] + red[3]) * (1.f / 1024.f);
  __syncthreads();
  const float mean = red[4];
  f32x4 d = x - mean;
  float s2 = d[0] * d[0] + d[1] * d[1] + d[2] * d[2] + d[3] * d[3];
  #pragma unroll
  for (int o = 32; o; o >>= 1) s2 += __shfl_down(s2, o);
  if ((tid & 63) == 0) red[tid >> 6] = s2;
  __syncthreads();
  if (tid == 0) red[5] = rsqrtf((red[0] + red[1] + red[2] + red[3]) * (1.f / 1024.f) + 1e-5f);
  __syncthreads();
  const float rstd = red[5];
  f32x4 gg = ((const f32x4*)g)[tid], bb = ((const f32x4*)be)[tid];
  bf16x4 o4;
  #pragma unroll
  for (int j = 0; j < 4; ++j) o4[j] = (bf16_t)(d[j] * rstd * gg[j] + bb[j]);
  ((bf16x4*)(out + (size_t)row * 1024))[tid] = o4;
}

// ---------------- epilogue: act 0/1 (bias/relu), act 5 (gate combine) -------------
__device__ __forceinline__ void epi_store(float vv, int row, int colb, int act,
                                          const float* bias, float* Cf, int ldcf, bf16_t* Cb,
                                          int ldcb, const bf16_t* zio, const bf16_t* hp,
                                          const float* xin) {
  if (act <= 1) {
    if (bias) vv += bias[colb];
    if (act == 1) vv = fmaxf(vv, 0.f);
    if (Cf) Cf[(size_t)row * ldcf + colb] = vv;
    if (Cb) Cb[(size_t)row * ldcb + colb] = (bf16_t)vv;
  } else {  // act 5: h=tanh(v+hp); o = x + z*(h-x)
    size_t e = (size_t)row * 1024 + colb;
    float hh = tanhf(vv + (float)hp[e]);
    float xx = xin[e], zz = (float)zio[e];
    float o = xx + zz * (hh - xx);
    if (Cf) Cf[(size_t)row * ldcf + colb] = o;
    if (Cb) Cb[(size_t)row * ldcb + colb] = (bf16_t)o;
  }
}

// ---------------- 128x64-tile MFMA GEMM, BK=64, XOR-swizzled LDS ----------------
__global__ __launch_bounds__(256) void gemm_n64(const bf16_t* __restrict__ A,
                                                const bf16_t* __restrict__ BT,
                                                const float* __restrict__ bias,
                                                float* __restrict__ Cf, int ldcf,
                                                bf16_t* __restrict__ Cb, int ldcb,
                                                const bf16_t* __restrict__ zio,
                                                const bf16_t* __restrict__ hp,
                                                const float* __restrict__ xin,
                                                int M, int N, int K, int act) {
  __shared__ bf16_t As[128 * 64];
  __shared__ bf16_t Bs[64 * 64];
  const int tid = threadIdx.x, lane = tid & 63, wid = tid >> 6;
  const int nx = gridDim.x;
  int flat = blockIdx.y * nx + blockIdx.x;
  int nwg = nx * gridDim.y;
  int q8 = nwg >> 3, r8 = nwg & 7;
  int xcd = flat & 7, idx = flat >> 3;
  int wg = (xcd < r8) ? xcd * (q8 + 1) + idx : r8 * (q8 + 1) + (xcd - r8) * q8 + idx;
  const int m0 = (wg / nx) * 128, n0 = (wg % nx) * 64;
  const int wm = wid * 32;
  const int mrow = lane & 15, kq = lane >> 4;
  f32x4 acc[2][4] = {};
  const int lrow = wid * 8 + (lane >> 3);
  const int swsrc = (((lane & 7) ^ ((lane >> 3) & 7)) << 3);
  for (int k0 = 0; k0 < K; k0 += 64) {
    #pragma unroll
    for (int i = 0; i < 4; ++i) {
      const bf16_t* ga = A + (size_t)(m0 + i * 32 + lrow) * K + k0 + swsrc;
      __builtin_amdgcn_global_load_lds((GPtr)ga, (LPtr)(&As[i * 2048 + wid * 512]), 16, 0, 0);
    }
    #pragma unroll
    for (int i = 0; i < 2; ++i) {
      const bf16_t* gb = BT + (size_t)(n0 + i * 32 + lrow) * K + k0 + swsrc;
      __builtin_amdgcn_global_load_lds((GPtr)gb, (LPtr)(&Bs[i * 2048 + wid * 512]), 16, 0, 0);
    }
    __syncthreads();
    bf16x8 af[2][2], bfr[4][2];
    #pragma unroll
    for (int i = 0; i < 2; ++i) {
      int row = wm + i * 16 + mrow;
      #pragma unroll
      for (int ks = 0; ks < 2; ++ks)
        af[i][ks] = *(const bf16x8*)&As[row * 64 + ((ks * 32 + kq * 8) ^ ((row & 7) << 3))];
    }
    #pragma unroll
    for (int j = 0; j < 4; ++j) {
      int row = j * 16 + mrow;
      #pragma unroll
      for (int ks = 0; ks < 2; ++ks)
        bfr[j][ks] = *(const bf16x8*)&Bs[row * 64 + ((ks * 32 + kq * 8) ^ ((row & 7) << 3))];
    }
    #pragma unroll
    for (int i = 0; i < 2; ++i)
      #pragma unroll
      for (int j = 0; j < 4; ++j)
        #pragma unroll
        for (int ks = 0; ks < 2; ++ks)
          acc[i][j] = __builtin_amdgcn_mfma_f32_16x16x32_bf16(af[i][ks], bfr[j][ks], acc[i][j],
                                                              0, 0, 0);
    __syncthreads();
  }
  #pragma unroll
  for (int i = 0; i < 2; ++i)
    #pragma unroll
    for (int j = 0; j < 4; ++j) {
      int colb = n0 + j * 16 + mrow;
      #pragma unroll
      for (int r2 = 0; r2 < 4; ++r2) {
        int row = m0 + wm + i * 16 + kq * 4 + r2;
        epi_store(acc[i][j][r2], row, colb, act, bias, Cf, ldcf, Cb, ldcb, zio, hp, xin);
      }
    }
}

// ---------------- 8-phase 256^2 GEMM ----------------
template <int MH, int NH>
__device__ __forceinline__ void mfma_quad(f32x4 (&acc)[8][4], bf16x8 (&a)[4][2],
                                          bf16x8 (&bfr)[4][2]) {
  #pragma unroll
  for (int ii = 0; ii < 4; ++ii)
    #pragma unroll
    for (int jj = 0; jj < 2; ++jj)
      #pragma unroll
      for (int ks = 0; ks < 2; ++ks)
        acc[MH * 4 + ii][NH * 2 + jj] = __builtin_amdgcn_mfma_f32_16x16x32_bf16(
            a[ii][ks], bfr[NH * 2 + jj][ks], acc[MH * 4 + ii][NH * 2 + jj], 0, 0, 0);
}

#define PH_SYNC()                                                                             \
  __builtin_amdgcn_s_barrier();                                                               \
  asm volatile("s_waitcnt lgkmcnt(0)" ::: "memory");                                          \
  __builtin_amdgcn_sched_barrier(0);                                                          \
  __builtin_amdgcn_s_setprio(1)

#define PH_END()                                                                              \
  __builtin_amdgcn_s_setprio(0);                                                              \
  __builtin_amdgcn_s_barrier();                                                               \
  __builtin_amdgcn_sched_barrier(0)

#define PH_END_VM()                                                                           \
  __builtin_amdgcn_s_setprio(0);                                                              \
  asm volatile("s_waitcnt vmcnt(4)" ::: "memory");                                            \
  __builtin_amdgcn_s_barrier();                                                               \
  __builtin_amdgcn_sched_barrier(0)

// ACT: 0 bias, 1 bias+relu, 4 gate pass1 (N=3072: rx | z | hpart, block-uniform regions)
template <int ACT>
__global__ __launch_bounds__(512, 2) void gemm256(const bf16_t* __restrict__ A,
                                                  const bf16_t* __restrict__ BT,
                                                  const float* __restrict__ bias,
                                                  bf16_t* __restrict__ Cb,
                                                  bf16_t* __restrict__ zio,
                                                  bf16_t* __restrict__ hp,
                                                  const float* __restrict__ xin,
                                                  int M, int N, int K) {
  __shared__ bf16_t lds[65536];
  const int tid = threadIdx.x, lane = tid & 63, w = tid >> 6;
  const int mrow = lane & 15, kq = lane >> 4;
  const int nx = N >> 8;
  int nwg = gridDim.x;
  int flat = blockIdx.x;
  int q8 = nwg >> 3, r8 = nwg & 7;
  int xcd = flat & 7, idxb = flat >> 3;
  int wg = (xcd < r8) ? xcd * (q8 + 1) + idxb : r8 * (q8 + 1) + (xcd - r8) * q8 + idxb;
  const int m0 = (wg / nx) * 256, n0 = (wg % nx) * 256;

  const bf16_t* pA = A + (size_t)m0 * K;
  const bf16_t* pB = BT + (size_t)n0 * K;

  auto stage = [&](const bf16_t* base, int kt, int hh, int buf, int area) {
    #pragma unroll
    for (int li = 0; li < 2; ++li) {
      int row = li * 64 + w * 8 + (lane >> 3);
      const bf16_t* src =
          base + (size_t)(hh * 128 + row) * K + kt * 64 + (((lane & 7) ^ (lane >> 3)) << 3);
      __builtin_amdgcn_global_load_lds(
          (GPtr)src, (LPtr)&lds[buf * 32768 + area * 16384 + hh * 8192 + li * 4096 + w * 512],
          16, 0, 0);
    }
  };
  auto ldA = [&](int buf, int i, int ks) -> bf16x8 {
    int row = i * 16 + mrow;
    int off = (row << 6) + ((ks * 32 + kq * 8) ^ ((row & 7) << 3));
    return *(const bf16x8*)&lds[buf * 32768 + (w >> 2) * 8192 + off];
  };
  auto ldB = [&](int buf, int j, int ks) -> bf16x8 {
    int row = (w & 1) * 64 + j * 16 + mrow;
    int off = (row << 6) + ((ks * 32 + kq * 8) ^ ((row & 7) << 3));
    return *(const bf16x8*)&lds[buf * 32768 + 16384 + ((w & 3) >> 1) * 8192 + off];
  };

  f32x4 acc[8][4] = {};
  bf16x8 a[4][2], bfr[4][2];

  const int KT = K >> 6;
  stage(pA, 0, 0, 0, 0);
  stage(pA, 0, 1, 0, 0);
  stage(pB, 0, 0, 0, 1);
  stage(pB, 0, 1, 0, 1);
  stage(pB, 1, 0, 1, 1);
  stage(pB, 1, 1, 1, 1);
  asm volatile("s_waitcnt vmcnt(4)" ::: "memory");
  __builtin_amdgcn_s_barrier();
  __builtin_amdgcn_sched_barrier(0);

  for (int it = 0; it < KT / 2; ++it) {
    int kt = 2 * it;
    int ktA1 = min(kt + 1, KT - 1);
    int kt2 = min(kt + 2, KT - 1);
    int kt3 = min(kt + 3, KT - 1);
    #pragma unroll
    for (int ii = 0; ii < 4; ++ii) { a[ii][0] = ldA(0, ii, 0); a[ii][1] = ldA(0, ii, 1); }
    #pragma unroll
    for (int jj = 0; jj < 2; ++jj) { bfr[jj][0] = ldB(0, jj, 0); bfr[jj][1] = ldB(0, jj, 1); }
    stage(pA, ktA1, 0, 1, 0);
    PH_SYNC(); mfma_quad<0, 0>(acc, a, bfr); PH_END();
    #pragma unroll
    for (int jj = 0; jj < 2; ++jj) { bfr[2 + jj][0] = ldB(0, 2 + jj, 0); bfr[2 + jj][1] = ldB(0, 2 + jj, 1); }
    stage(pA, ktA1, 1, 1, 0);
    PH_SYNC(); mfma_quad<0, 1>(acc, a, bfr); PH_END();
    #pragma unroll
    for (int ii = 0; ii < 4; ++ii) { a[ii][0] = ldA(0, 4 + ii, 0); a[ii][1] = ldA(0, 4 + ii, 1); }
    stage(pB, kt2, 0, 0, 1);
    PH_SYNC(); mfma_quad<1, 0>(acc, a, bfr); PH_END();
    stage(pB, kt2, 1, 0, 1);
    PH_SYNC(); mfma_quad<1, 1>(acc, a, bfr); PH_END_VM();
    #pragma unroll
    for (int ii = 0; ii < 4; ++ii) { a[ii][0] = ldA(1, ii, 0); a[ii][1] = ldA(1, ii, 1); }
    #pragma unroll
    for (int jj = 0; jj < 2; ++jj) { bfr[jj][0] = ldB(1, jj, 0); bfr[jj][1] = ldB(1, jj, 1); }
    stage(pA, kt2, 0, 0, 0);
    PH_SYNC(); mfma_quad<0, 0>(acc, a, bfr); PH_END();
    #pragma unroll
    for (int jj = 0; jj < 2; ++jj) { bfr[2 + jj][0] = ldB(1, 2 + jj, 0); bfr[2 + jj][1] = ldB(1, 2 + jj, 1); }
    stage(pA, kt2, 1, 0, 0);
    PH_SYNC(); mfma_quad<0, 1>(acc, a, bfr); PH_END();
    #pragma unroll
    for (int ii = 0; ii < 4; ++ii) { a[ii][0] = ldA(1, 4 + ii, 0); a[ii][1] = ldA(1, 4 + ii, 1); }
    stage(pB, kt3, 0, 1, 1);
    PH_SYNC(); mfma_quad<1, 0>(acc, a, bfr); PH_END();
    stage(pB, kt3, 1, 1, 1);
    PH_SYNC(); mfma_quad<1, 1>(acc, a, bfr); PH_END_VM();
  }

  if (ACT <= 1) {
    #pragma unroll
    for (int i = 0; i < 8; ++i)
      #pragma unroll
      for (int j = 0; j < 4; ++j) {
        int colb = n0 + (w & 3) * 64 + j * 16 + mrow;
        float bv = bias ? bias[colb] : 0.f;
        #pragma unroll
        for (int r2 = 0; r2 < 4; ++r2) {
          int row = m0 + (w >> 2) * 128 + i * 16 + kq * 4 + r2;
          float vv = acc[i][j][r2] + bv;
          if (ACT == 1) vv = fmaxf(vv, 0.f);
          Cb[(size_t)row * N + colb] = (bf16_t)vv;
        }
      }
  } else {  // ACT == 4: block-uniform regions (1024-wide)
    if (n0 < 1024) {
      #pragma unroll
      for (int i = 0; i < 8; ++i)
        #pragma unroll
        for (int j = 0; j < 4; ++j) {
          int colb = n0 + (w & 3) * 64 + j * 16 + mrow;
          #pragma unroll
          for (int r2 = 0; r2 < 4; ++r2) {
            int row = m0 + (w >> 2) * 128 + i * 16 + kq * 4 + r2;
            float r = 1.f / (1.f + __expf(-acc[i][j][r2]));
            Cb[(size_t)row * 1024 + colb] = (bf16_t)(r * xin[(size_t)row * 1024 + colb]);
          }
        }
    } else if (n0 < 2048) {
      #pragma unroll
      for (int i = 0; i < 8; ++i)
        #pragma unroll
        for (int j = 0; j < 4; ++j) {
          int colz = n0 - 1024 + (w & 3) * 64 + j * 16 + mrow;
          float bv = bias[colz];
          #pragma unroll
          for (int r2 = 0; r2 < 4; ++r2) {
            int row = m0 + (w >> 2) * 128 + i * 16 + kq * 4 + r2;
            float z = 1.f / (1.f + __expf(-(acc[i][j][r2] - bv)));
            zio[(size_t)row * 1024 + colz] = (bf16_t)z;
          }
        }
    } else {
      #pragma unroll
      for (int i = 0; i < 8; ++i)
        #pragma unroll
        for (int j = 0; j < 4; ++j) {
          int colh = n0 - 2048 + (w & 3) * 64 + j * 16 + mrow;
          #pragma unroll
          for (int r2 = 0; r2 < 4; ++r2) {
            int row = m0 + (w >> 2) * 128 + i * 16 + kq * 4 + r2;
            hp[(size_t)row * 1024 + colh] = (bf16_t)acc[i][j][r2];
          }
        }
    }
  }
}

// ---------------- fused attn prep: kc / vT / rpT (kv stride 2048) ----------------
__global__ __launch_bounds__(256) void prep_kernel(const bf16_t* __restrict__ kv,
                                                   const bf16_t* __restrict__ rp,
                                                   bf16_t* __restrict__ kc,
                                                   bf16_t* __restrict__ vT,
                                                   bf16_t* __restrict__ rpT) {
  int y = blockIdx.y;
  int tid = threadIdx.x;
  if (y < 128) {  // kc[bh][f][64]
    int bh = y, f0 = blockIdx.x * 64;
    int b = bh >> 4, h = bh & 15;
    int f = f0 + (tid >> 2), d0 = (tid & 3) * 16;
    const bf16_t* src = kv + (size_t)(f * 8 + b) * 2048 + h * 64 + d0;
    bf16_t* dst = kc + ((size_t)bh * 1024 + f) * 64 + d0;
    *(bf16x8*)dst = *(const bf16x8*)src;
    *(bf16x8*)(dst + 8) = *(const bf16x8*)(src + 8);
  } else if (y < 256) {  // vT[bh][d][f]
    int bh = y - 128, ft = blockIdx.x;
    int b = bh >> 4, h = bh & 15;
    __shared__ bf16_t t[64][68];
    {
      int dq = (tid & 15) * 4, fr = tid >> 4;
      #pragma unroll
      for (int p = 0; p < 4; ++p) {
        int fi = fr + p * 16;
        const bf16_t* src = kv + ((size_t)((ft * 64 + fi) * 8 + b)) * 2048 + 1024 + h * 64 + dq;
        *(bf16x4*)&t[fi][dq] = *(const bf16x4*)src;
      }
    }
    __syncthreads();
    {
      int fl = tid & 63, dr = tid >> 6;
      #pragma unroll
      for (int p = 0; p < 16; ++p) {
        int d = dr + p * 4;
        vT[((size_t)(bh * 64 + d)) * 1024 + ft * 64 + fl] = t[fl][d];
      }
    }
  } else {  // rpT[h][j][64]
    int h = y - 256, j0 = blockIdx.x * 64;
    int j = j0 + (tid >> 2), d0 = (tid & 3) * 16;
    const bf16_t* src = rp + (size_t)j * 1024 + h * 64 + d0;
    bf16_t* dst = rpT + ((size_t)h * 1024 + j) * 64 + d0;
    *(bf16x8*)dst = *(const bf16x8*)src;
    *(bf16x8*)(dst + 8) = *(const bf16x8*)(src + 8);
  }
}

// ---------------- attention v6 (round-14 known-good) ----------------
__global__ __launch_bounds__(256) void attn_kernel(const bf16_t* __restrict__ q,
                                                   const bf16_t* __restrict__ kc,
                                                   const bf16_t* __restrict__ rpT,
                                                   const bf16_t* __restrict__ vT,
                                                   const float* __restrict__ u,
                                                   const float* __restrict__ v,
                                                   bf16_t* __restrict__ av) {
  const int bh = blockIdx.x, st = blockIdx.y;
  const int b = bh >> 4, h = bh & 15;
  const int s0 = st * 16;
  const int tid = threadIdx.x, lane = tid & 63, w = tid >> 6;
  const int mrow = lane & 15, kq = lane >> 4;

  __shared__ bf16_t sc[16 * 1032];
  __shared__ bf16_t slots[4 * 2 * 1024];
  __shared__ float rrecip[16];

  bf16x8 afu[2], afv[2];
  {
    const bf16_t* qp = q + ((size_t)((s0 + mrow) * 8 + b)) * 1024 + h * 64 + kq * 8;
    bf16x8 q0 = *(const bf16x8*)qp;
    bf16x8 q1 = *(const bf16x8*)(qp + 32);
    const float* ub = u + h * 64 + kq * 8;
    const float* vb = v + h * 64 + kq * 8;
    #pragma unroll
    for (int j = 0; j < 8; ++j) {
      float f0 = (float)q0[j], f1 = (float)q1[j];
      afu[0][j] = (bf16_t)((f0 + ub[j]) * 0.125f);
      afu[1][j] = (bf16_t)((f1 + ub[32 + j]) * 0.125f);
      afv[0][j] = (bf16_t)((f0 + vb[j]) * 0.125f);
      afv[1][j] = (bf16_t)((f1 + vb[32 + j]) * 0.125f);
    }
  }

  const int nf1 = (s0 + 543) >> 4;
  const int jt0 = (s0 >= 496) ? 0 : ((496 - s0) >> 4);
  const bf16_t* kcb = kc + (size_t)bh * 65536;
  const bf16_t* rpb = rpT + (size_t)h * 65536;
  const int swzel = ((lane & 7) ^ (lane >> 3)) * 8;
  const int rdsw = (mrow & 7) << 4;

  auto issueT = [&](const bf16_t* base, int idx, int tile) {
    int slot = idx & 1;
    #pragma unroll
    for (int li = 0; li < 2; ++li) {
      const bf16_t* src = base + (size_t)(tile * 16 + li * 8 + (lane >> 3)) * 64 + swzel;
      __builtin_amdgcn_global_load_lds((GPtr)src,
                                       (LPtr)&slots[w * 2048 + slot * 1024 + li * 512], 16, 0, 0);
    }
  };
  auto slotB = [&](int idx, bf16x8& b0, bf16x8& b1) {
    const bf16_t* sb = &slots[w * 2048 + (idx & 1) * 1024];
    b0 = *(const bf16x8*)&sb[(mrow * 128 + ((kq * 16) ^ rdsw)) >> 1];
    b1 = *(const bf16x8*)&sb[(mrow * 128 + ((64 + kq * 16) ^ rdsw)) >> 1];
  };

  // phase 1: content scores
  {
    int ncw = (nf1 > w) ? (nf1 - w + 3) >> 2 : 0;
    if (ncw > 0) issueT(kcb, 0, w);
    if (ncw > 1) issueT(kcb, 1, w + 4);
    for (int i = 0; i < ncw; ++i) {
      if (i + 1 < ncw) asm volatile("s_waitcnt vmcnt(2)" ::: "memory");
      else asm volatile("s_waitcnt vmcnt(0)" ::: "memory");
      __builtin_amdgcn_sched_barrier(0);
      bf16x8 b0, b1;
      slotB(i, b0, b1);
      f32x4 cc = {0.f, 0.f, 0.f, 0.f};
      cc = __builtin_amdgcn_mfma_f32_16x16x32_bf16(afu[0], b0, cc, 0, 0, 0);
      cc = __builtin_amdgcn_mfma_f32_16x16x32_bf16(afu[1], b1, cc, 0, 0, 0);
      int fb = (w + 4 * i) * 16 + mrow;
      #pragma unroll
      for (int r2 = 0; r2 < 4; ++r2) sc[(kq * 4 + r2) * 1032 + fb] = (bf16_t)cc[r2];
      __builtin_amdgcn_sched_barrier(0);
      if (i + 2 < ncw) issueT(kcb, i + 2, w + 4 * (i + 2));
    }
  }
  __syncthreads();

  // phase 2: position scores, RMW scatter-add at f = j - 511 + s
  {
    int navail = 64 - jt0;
    int npw = (navail > w) ? (navail - w + 3) >> 2 : 0;
    if (npw > 0) issueT(rpb, 0, jt0 + w);
    if (npw > 1) issueT(rpb, 1, jt0 + w + 4);
    for (int i = 0; i < npw; ++i) {
      if (i + 1 < npw) asm volatile("s_waitcnt vmcnt(2)" ::: "memory");
      else asm volatile("s_waitcnt vmcnt(0)" ::: "memory");
      __builtin_amdgcn_sched_barrier(0);
      bf16x8 b0, b1;
      slotB(i, b0, b1);
      f32x4 cc = {0.f, 0.f, 0.f, 0.f};
      cc = __builtin_amdgcn_mfma_f32_16x16x32_bf16(afv[0], b0, cc, 0, 0, 0);
      cc = __builtin_amdgcn_mfma_f32_16x16x32_bf16(afv[1], b1, cc, 0, 0, 0);
      int jb = (jt0 + w + 4 * i) * 16 + mrow - 511 + s0;
      #pragma unroll
      for (int r2 = 0; r2 < 4; ++r2) {
        int srow = kq * 4 + r2;
        int f = jb + srow;
        if (f >= 0) {
          float old = (float)sc[srow * 1032 + f];
          sc[srow * 1032 + f] = (bf16_t)(old + cc[r2]);
        }
      }
      __builtin_amdgcn_sched_barrier(0);
      if (i + 2 < npw) issueT(rpb, i + 2, jt0 + w + 4 * (i + 2));
    }
  }
  __syncthreads();

  // phase 3: masked softmax
  #pragma unroll
  for (int rr = 0; rr < 4; ++rr) {
    int row = w * 4 + rr;
    int fmx = s0 + row;
    bf16x8 c0 = *(const bf16x8*)&sc[row * 1032 + lane * 8];
    bf16x8 c1 = *(const bf16x8*)&sc[row * 1032 + 512 + lane * 8];
    float lo[8], hi[8];
    float mx = -1e30f;
    #pragma unroll
    for (int i = 0; i < 8; ++i) {
      lo[i] = (float)c0[i];
      mx = fmaxf(mx, lo[i]);
    }
    #pragma unroll
    for (int i = 0; i < 8; ++i) {
      hi[i] = (float)c1[i];
      if (lane * 8 + i <= fmx) mx = fmaxf(mx, hi[i]);
    }
    #pragma unroll
    for (int o = 32; o; o >>= 1) mx = fmaxf(mx, __shfl_xor(mx, o));
    float sum = 0.f;
    bf16x8 e0, e1;
    #pragma unroll
    for (int i = 0; i < 8; ++i) {
      float e = __expf(lo[i] - mx);
      sum += e;
      e0[i] = (bf16_t)e;
    }
    #pragma unroll
    for (int i = 0; i < 8; ++i) {
      float e = (lane * 8 + i <= fmx) ? __expf(hi[i] - mx) : 0.f;
      sum += e;
      e1[i] = (bf16_t)e;
    }
    *(bf16x8*)&sc[row * 1032 + lane * 8] = e0;
    *(bf16x8*)&sc[row * 1032 + 512 + lane * 8] = e1;
    #pragma unroll
    for (int o = 32; o; o >>= 1) sum += __shfl_xor(sum, o);
    if (lane == 0) rrecip[row] = 1.f / sum;
  }
  __syncthreads();

  // phase 4: AV
  {
    int nkk = (s0 + 559) >> 5;
    const bf16_t* vtb = vT + (size_t)(bh * 64 + w * 16) * 1024;
    auto issueV = [&](int idx, int kk) {
      int slot = idx & 1;
      const bf16_t* src = vtb + (size_t)(lane >> 2) * 1024 + kk * 32 +
                          (((lane & 3) ^ ((lane >> 2) & 3)) << 3);
      __builtin_amdgcn_global_load_lds((GPtr)src, (LPtr)&slots[w * 2048 + slot * 1024], 16, 0, 0);
    };
    f32x4 acc = {0.f, 0.f, 0.f, 0.f};
    issueV(0, 0);
    if (nkk > 1) issueV(1, 1);
    for (int kk = 0; kk < nkk; ++kk) {
      if (kk + 1 < nkk) asm volatile("s_waitcnt vmcnt(1)" ::: "memory");
      else asm volatile("s_waitcnt vmcnt(0)" ::: "memory");
      __builtin_amdgcn_sched_barrier(0);
      const bf16_t* sb = &slots[w * 2048 + (kk & 1) * 1024];
      bf16x8 bv = *(const bf16x8*)&sb[mrow * 32 + ((kq ^ (mrow & 3)) << 3)];
      bf16x8 af = *(const bf16x8*)&sc[mrow * 1032 + kk * 32 + kq * 8];
      acc = __builtin_amdgcn_mfma_f32_16x16x32_bf16(af, bv, acc, 0, 0, 0);
      __builtin_amdgcn_sched_barrier(0);
      if (kk + 2 < nkk) issueV(kk + 2, kk + 2);
    }
    #pragma unroll
    for (int r2 = 0; r2 < 4; ++r2) {
      int srow = kq * 4 + r2;
      float ov = acc[r2] * rrecip[srow];
      av[((size_t)((s0 + srow) * 8 + b)) * 1024 + h * 64 + w * 16 + mrow] = (bf16_t)ov;
    }
  }
}

// ---------------- host ----------------
extern "C" void kernel_launch(void* const* d_in, const int* in_sizes, int n_in,
                              void* d_out, int out_size, void* d_ws, size_t ws_size,
                              hipStream_t stream) {
  const float* inputs = (const float*)d_in[0];
  const float* pos_emb = (const float*)d_in[1];
  const float* memory = (const float*)d_in[2];
  const float* u = (const float*)d_in[3];
  const float* v = (const float*)d_in[4];
  const float* Wkv = (const float*)d_in[6];
  const float* bkv = (const float*)d_in[7];
  const float* Wq = (const float*)d_in[8];
  const float* bq = (const float*)d_in[9];
  const float* Wpos = (const float*)d_in[10];
  const float* bpos = (const float*)d_in[11];
  const float* Wproj = (const float*)d_in[12];
  const float* bproj = (const float*)d_in[13];
  const float* ln1_g = (const float*)d_in[14];
  const float* ln1_b = (const float*)d_in[15];
  const float* ln2_g = (const float*)d_in[16];
  const float* ln2_b = (const float*)d_in[17];
  const float* g1_bg = (const float*)d_in[24];
  const float* g2_bg = (const float*)d_in[31];
  const float* mlp_W1 = (const float*)d_in[32];
  const float* mlp_b1 = (const float*)d_in[33];
  const float* mlp_W2 = (const float*)d_in[34];
  const float* mlp_b2 = (const float*)d_in[35];

  char* ws = (char*)d_ws;
  const size_t MB = 1ull << 20;
  bf16_t* x1 = (bf16_t*)(ws + 0);
  bf16_t* kvb = (bf16_t*)(ws + 16 * MB);
  bf16_t* qb = (bf16_t*)(ws + 48 * MB);
  bf16_t* peb = (bf16_t*)(ws + 56 * MB);
  bf16_t* rposb = (bf16_t*)(ws + 58 * MB);
  bf16_t* kc = (bf16_t*)(ws + 60 * MB);
  bf16_t* vTb = (bf16_t*)(ws + 76 * MB);
  bf16_t* rpTb = (bf16_t*)(ws + 92 * MB);
  bf16_t* avb = (bf16_t*)(ws + 94 * MB);
  bf16_t* yx1 = (bf16_t*)(ws + 102 * MB);
  bf16_t* rxb = (bf16_t*)(ws + 0);
  bf16_t* zb = (bf16_t*)(ws + 8 * MB);
  bf16_t* hpb = (bf16_t*)(ws + 16 * MB);
  float* o1f = (float*)(ws + 24 * MB);
  bf16_t* x2b = (bf16_t*)(ws + 40 * MB);
  bf16_t* m1b = (bf16_t*)(ws + 48 * MB);
  bf16_t* yx2 = (bf16_t*)(ws + 80 * MB);
  bf16_t* WkvT = (bf16_t*)(ws + 134 * MB);
  bf16_t* WqT = (bf16_t*)(ws + 138 * MB);
  bf16_t* WposT = (bf16_t*)(ws + 140 * MB);
  bf16_t* WprojT = (bf16_t*)(ws + 142 * MB);
  bf16_t* W1T = (bf16_t*)(ws + 144 * MB);
  bf16_t* W2T = (bf16_t*)(ws + 152 * MB);
  bf16_t* g1p = (bf16_t*)(ws + 160 * MB);
  bf16_t* g1ug = (bf16_t*)(ws + 172 * MB);
  bf16_t* g2p = (bf16_t*)(ws + 174 * MB);
  bf16_t* g2ug = (bf16_t*)(ws + 186 * MB);

  WtArgs wa;
  {
    const float* srcs[NWT] = {Wkv, Wq, Wpos, Wproj, mlp_W1, mlp_W2,
                              (const float*)d_in[18], (const float*)d_in[19],
                              (const float*)d_in[20], (const float*)d_in[21],
                              (const float*)d_in[22], nullptr, (const float*)d_in[23],
                              (const float*)d_in[25], (const float*)d_in[26],
                              (const float*)d_in[27], (const float*)d_in[28],
                              (const float*)d_in[29], nullptr, (const float*)d_in[30]};
    bf16_t* dsts[NWT] = {WkvT, WqT, WposT, WprojT, W1T, W2T,
                         g1p, g1p + 1024, g1p + (size_t)1024 * 2048,
                         g1p + (size_t)1024 * 2048 + 1024, g1p + (size_t)2048 * 2048,
                         g1p + (size_t)2048 * 2048 + 1024, g1ug,
                         g2p, g2p + 1024, g2p + (size_t)1024 * 2048,
                         g2p + (size_t)1024 * 2048 + 1024, g2p + (size_t)2048 * 2048,
                         g2p + (size_t)2048 * 2048 + 1024, g2ug};
    int kds[NWT] = {1024, 1024, 1024, 1024, 1024, 4096, 1024, 1024, 1024, 1024,
                    1024, 1024, 1024, 1024, 1024, 1024, 1024, 1024, 1024, 1024};
    int nds[NWT] = {2048, 1024, 1024, 1024, 4096, 1024, 1024, 1024, 1024, 1024,
                    1024, 1024, 1024, 1024, 1024, 1024, 1024, 1024, 1024, 1024};
    int lds_[NWT] = {1024, 1024, 1024, 1024, 1024, 4096, 2048, 2048, 2048, 2048,
                     2048, 2048, 1024, 2048, 2048, 2048, 2048, 2048, 2048, 1024};
    int cum = 0;
    for (int i = 0; i < NWT; ++i) {
      wa.src[i] = srcs[i];
      wa.dst[i] = dsts[i];
      wa.kdim[i] = kds[i];
      wa.ndim[i] = nds[i];
      wa.ld[i] = lds_[i];
      cum += (nds[i] >> 6) * (kds[i] >> 6);
      wa.tile_end[i] = cum;
    }
    wt_batch<<<cum, 256, 0, stream>>>(wa);
  }

  cvt_kernel<<<1024, 256, 0, stream>>>(pos_emb, peb, 262144, 1024);
  // LN1 with fused inputs->bf16 side-store into yx1 x-half
  ln_kernel<<<8192, 256, 0, stream>>>(memory, inputs, 4096, ln1_g, ln1_b, x1, yx1 + 1024, 2048);

  auto g64 = [&](const bf16_t* A, const bf16_t* BT, const float* bias, float* Cf, int ldcf,
                 bf16_t* Cb, int ldcb, const bf16_t* zio, const bf16_t* hp, const float* xin,
                 int M, int N, int K, int act) {
    gemm_n64<<<dim3(N / 64, M / 128), 256, 0, stream>>>(A, BT, bias, Cf, ldcf, Cb, ldcb, zio, hp,
                                                        xin, M, N, K, act);
  };

  gemm256<0><<<(8192 / 256) * (2048 / 256), 512, 0, stream>>>(x1, WkvT, bkv, kvb, nullptr,
                                                              nullptr, nullptr, 8192, 2048, 1024);
  g64(x1 + (size_t)4096 * 1024, WqT, bq, nullptr, 0, qb, 1024, nullptr, nullptr, nullptr, 4096,
      1024, 1024, 0);
  g64(peb, WposT, bpos, nullptr, 0, rposb, 1024, nullptr, nullptr, nullptr, 1024, 1024, 1024, 0);
  prep_kernel<<<dim3(16, 272), 256, 0, stream>>>(kvb, rposb, kc, vTb, rpTb);
  attn_kernel<<<dim3(128, 32), 256, 0, stream>>>(qb, kc, rpTb, vTb, u, v, avb);
  g64(avb, WprojT, bproj, nullptr, 0, yx1, 2048, nullptr, nullptr, nullptr, 4096, 1024, 1024, 1);

  // GRU gate 1
  gemm256<4><<<(4096 / 256) * (3072 / 256), 512, 0, stream>>>(yx1, g1p, g1_bg, rxb, zb, hpb,
                                                              inputs, 4096, 3072, 2048);
  g64(rxb, g1ug, nullptr, o1f, 1024, yx2 + 1024, 2048, zb, hpb, inputs, 4096, 1024, 1024, 5);

  ln_kernel<<<4096, 256, 0, stream>>>(o1f, nullptr, 1 << 30, ln2_g, ln2_b, x2b, nullptr, 0);
  gemm256<1><<<(4096 / 256) * (4096 / 256), 512, 0, stream>>>(x2b, W1T, mlp_b1, m1b, nullptr,
                                                              nullptr, nullptr, 4096, 4096, 1024);
  g64(m1b, W2T, mlp_b2, nullptr, 0, yx2, 2048, nullptr, nullptr, nullptr, 4096, 1024, 4096, 1);

  // GRU gate 2
  gemm256<4><<<(4096 / 256) * (3072 / 256), 512, 0, stream>>>(yx2, g2p, g2_bg, rxb, zb, hpb, o1f,
                                                              4096, 3072, 2048);
  g64(rxb, g2ug, nullptr, (float*)d_out, 1024, nullptr, 0, zb, hpb, o1f, 4096, 1024, 1024, 5);
}